// Round 16
// baseline (207.200 us; speedup 1.0000x reference)
//
#include <hip/hip_runtime.h>
#include <math.h>

#define LQ 22223
#define NH 8
#define NL 4
#define NP 4
#define CDIM 256
#define MBLK 348              // ceil(LQ/64)
// XCD-swizzled block counts: groups of 8 (one per XCD), 44 row-tiles per XCD
#define NBV  (176 * 8)        // v-GEMM:   4 bx per by  -> j in [0,176)
#define NBOA (264 * 8)        // oa-GEMM:  6 bx per by  -> j in [0,264)
#define LR 72                 // LDS row: 64 + 8 pad ushorts (144B, 16B-aligned, bank-stride 4)

typedef __attribute__((ext_vector_type(8))) short short8;
typedef __attribute__((ext_vector_type(4))) float f32x4;

__device__ __forceinline__ ushort f2bf(float f) {
    union { float f; unsigned u; } c; c.f = f;
    unsigned u = c.u;
    return (ushort)((u + 0x7fffu + ((u >> 16) & 1u)) >> 16);   // RNE
}
__device__ __forceinline__ float bflo(unsigned u) {
    union { unsigned u; float f; } c; c.u = u << 16; return c.f;
}
__device__ __forceinline__ float bfhi(unsigned u) {
    union { unsigned u; float f; } c; c.u = u & 0xffff0000u; return c.f;
}
__device__ __forceinline__ short8 cvt8(float4 f0, float4 f1) {
    short8 s;
    s[0] = (short)f2bf(f0.x); s[1] = (short)f2bf(f0.y);
    s[2] = (short)f2bf(f0.z); s[3] = (short)f2bf(f0.w);
    s[4] = (short)f2bf(f1.x); s[5] = (short)f2bf(f1.y);
    s[6] = (short)f2bf(f1.z); s[7] = (short)f2bf(f1.w);
    return s;
}

// ---------------------------------------------------------------------------
// Transpose+convert weights fp32 [K=256][N] -> bf16 [N][K].
// Wt_oa = concat(W_off rows, W_attn rows); bcat = concat(b_off, b_attn).
// ---------------------------------------------------------------------------
__global__ __launch_bounds__(256) void convert_wt(
    const float* __restrict__ Wv, const float* __restrict__ Wo,
    const float* __restrict__ Wu, const float* __restrict__ Wa,
    const float* __restrict__ bo, const float* __restrict__ ba,
    ushort* __restrict__ Tv, ushort* __restrict__ Toa,
    ushort* __restrict__ Tu, float* __restrict__ bcat)
{
    int idx = blockIdx.x * 256 + threadIdx.x;
    if (idx >= 229376) {
        int b = idx - 229376;
        if (b < 384) bcat[b] = (b < 256) ? bo[b] : ba[b - 256];
        return;
    }
    const float* W; ushort* T; int N; int local;
    if      (idx < 65536)  { W = Wv; T = Tv;          N = 256; local = idx; }
    else if (idx < 131072) { W = Wo; T = Toa;         N = 256; local = idx - 65536; }
    else if (idx < 196608) { W = Wu; T = Tu;          N = 256; local = idx - 131072; }
    else                   { W = Wa; T = Toa + 65536; N = 128; local = idx - 196608; }
    int k = local & 255;
    int n = local >> 8;
    T[n * 256 + k] = f2bf(W[k * N + n]);
}

// ---------------------------------------------------------------------------
// Fused dual GEMM, 64x64 tile, BK=64 (4 K-steps, HALF the barriers of the
// round-15 BK=32 version — round-11 counters showed the per-step
// vmcnt(0)+lgkmcnt(0) barrier drain is the dominant stall; round-12's
// 0-barrier extreme failed on TLP, this is the middle point), XCD-swizzled,
// LDS double-buffered, 4 blocks/CU (36.9 KB LDS, __launch_bounds__(256,4)
// -> VGPR cap 64 per the measured allocator model).
//   blocks [0, NBV):  v_bf = bf16(value @ Wt_val^T + b_val)  head-major out
//   blocks [NBV, ..): offattn = query @ Wt_oa^T + bcat; bx>=4 = logit tiles
//     with SOFTMAX FUSED via 16-lane __shfl_xor butterfly (verified r11/r15).
// ---------------------------------------------------------------------------
__global__ __launch_bounds__(256, 4) void gemm_dual(
    const float* __restrict__ value, const ushort* __restrict__ Wtv,
    const float* __restrict__ bv, ushort* __restrict__ Cv,
    const float* __restrict__ query, const ushort* __restrict__ Wtoa,
    const float* __restrict__ boa, float* __restrict__ Coa)
{
    __shared__ ushort As[2][64 * LR];
    __shared__ ushort Bs[2][64 * LR];

    int b = blockIdx.x;
    const float* A; const ushort* Bt; const float* bias;
    int bx, by; bool isv;
    const int xcd = b & 7;
    if (b < NBV) {
        isv = true;  A = value; Bt = Wtv;  bias = bv;
        const int j = b >> 3;
        bx = j & 3;  by = xcd + 8 * (j >> 2);
    } else {
        isv = false; A = query; Bt = Wtoa; bias = boa;
        const int j = (b - NBV) >> 3;
        bx = j % 6;  by = xcd + 8 * (j / 6);
    }
    if (by >= MBLK) return;

    const int tid = threadIdx.x;
    const int w = tid >> 6;
    const int l = tid & 63;
    const int bm = by * 64;
    const int bn = bx * 64;

    const int r = tid >> 2;       // 0..63 staging row
    const int c = tid & 3;        // 16-col group

    const int lm   = l & 15;
    const int m_l  = (w << 4) + lm;
    const int koff = (l >> 4) << 3;

    const bool arow_ok = (bm + r) < LQ;
    const float*  Ap = A  + (size_t)(bm + r) * 256 + c * 16;
    const ushort* Bp = Bt + (size_t)(bn + r) * 256 + c * 16;

    auto ldA2 = [&](int k0, short8& lo, short8& hi) {
        lo = short8{0,0,0,0,0,0,0,0}; hi = lo;
        if (arow_ok) {
            const float4 f0 = *reinterpret_cast<const float4*>(Ap + k0);
            const float4 f1 = *reinterpret_cast<const float4*>(Ap + k0 + 4);
            lo = cvt8(f0, f1);
            const float4 f2 = *reinterpret_cast<const float4*>(Ap + k0 + 8);
            const float4 f3 = *reinterpret_cast<const float4*>(Ap + k0 + 12);
            hi = cvt8(f2, f3);
        }
    };

    short8 aLo, aHi, bLo, bHi;
    ldA2(0, aLo, aHi);
    bLo = *reinterpret_cast<const short8*>(Bp);
    bHi = *reinterpret_cast<const short8*>(Bp + 8);
    *reinterpret_cast<short8*>(&As[0][r * LR + c * 16])     = aLo;
    *reinterpret_cast<short8*>(&As[0][r * LR + c * 16 + 8]) = aHi;
    *reinterpret_cast<short8*>(&Bs[0][r * LR + c * 16])     = bLo;
    *reinterpret_cast<short8*>(&Bs[0][r * LR + c * 16 + 8]) = bHi;

    f32x4 acc[4] = {};

    #pragma unroll
    for (int k = 0; k < 4; ++k) {
        __syncthreads();
        if (k < 3) {
            ldA2((k + 1) * 64, aLo, aHi);
            bLo = *reinterpret_cast<const short8*>(Bp + (k + 1) * 64);
            bHi = *reinterpret_cast<const short8*>(Bp + (k + 1) * 64 + 8);
        }
        const int cur = k & 1;
        #pragma unroll
        for (int kh = 0; kh < 2; ++kh) {
            const int ko = kh * 32 + koff;
            const short8 af = *reinterpret_cast<const short8*>(&As[cur][m_l * LR + ko]);
            #pragma unroll
            for (int t = 0; t < 4; ++t) {
                const short8 bf = *reinterpret_cast<const short8*>(
                    &Bs[cur][(t * 16 + lm) * LR + ko]);
                acc[t] = __builtin_amdgcn_mfma_f32_16x16x32_bf16(af, bf, acc[t], 0, 0, 0);
            }
        }
        if (k < 3) {
            const int nxt = cur ^ 1;
            *reinterpret_cast<short8*>(&As[nxt][r * LR + c * 16])     = aLo;
            *reinterpret_cast<short8*>(&As[nxt][r * LR + c * 16 + 8]) = aHi;
            *reinterpret_cast<short8*>(&Bs[nxt][r * LR + c * 16])     = bLo;
            *reinterpret_cast<short8*>(&Bs[nxt][r * LR + c * 16 + 8]) = bHi;
        }
    }

    const int row0 = bm + (w << 4) + ((l >> 4) << 2);

    if (!isv && bx >= 4) {
        // ---- fused softmax epilogue (logit cols 256..383; verified r11/r15)
        #pragma unroll
        for (int t = 0; t < 4; ++t) {
            const int col = bn + t * 16 + lm;
            const float bs = bias[col];
            #pragma unroll
            for (int i = 0; i < 4; ++i) {
                const int row = row0 + i;
                const float L = acc[t][i] + bs;
                float mx = L;
                #pragma unroll
                for (int s = 1; s < 16; s <<= 1)
                    mx = fmaxf(mx, __shfl_xor(mx, s));
                const float e = expf(L - mx);
                float sum = e;
                #pragma unroll
                for (int s = 1; s < 16; s <<= 1)
                    sum += __shfl_xor(sum, s);
                if (row < LQ)
                    Coa[(size_t)row * 384 + col] = e / sum;
            }
        }
    } else {
        #pragma unroll
        for (int t = 0; t < 4; ++t) {
            const int col = bn + t * 16 + lm;
            const float bs = bias[col];
            #pragma unroll
            for (int i = 0; i < 4; ++i) {
                const int row = row0 + i;
                if (row < LQ) {
                    const float o = acc[t][i] + bs;
                    if (isv) {
                        // head-major: [h][row][ch32]
                        const int head = col >> 5;
                        const int ch   = col & 31;
                        Cv[(size_t)head * ((size_t)LQ * 32) + (size_t)row * 32 + ch] = f2bf(o);
                    } else {
                        Coa[(size_t)row * 384 + col] = o;
                    }
                }
            }
        }
    }
}

// ---------------------------------------------------------------------------
// Output GEMM (bf16 A), same BK=64 structure. N=256, fp32 out.
// ---------------------------------------------------------------------------
__global__ __launch_bounds__(256, 4) void gemm_out(
    const ushort* __restrict__ A, const ushort* __restrict__ Bt,
    const float* __restrict__ bias, float* __restrict__ C)
{
    __shared__ ushort As[2][64 * LR];
    __shared__ ushort Bs[2][64 * LR];

    const int b = blockIdx.x;
    const int xcd = b & 7;
    const int j = b >> 3;
    const int bx = j & 3;
    const int by = xcd + 8 * (j >> 2);
    if (by >= MBLK) return;

    const int tid = threadIdx.x;
    const int w = tid >> 6;
    const int l = tid & 63;
    const int bm = by * 64;
    const int bn = bx * 64;

    const int r = tid >> 2;
    const int c = tid & 3;

    const int lm   = l & 15;
    const int m_l  = (w << 4) + lm;
    const int koff = (l >> 4) << 3;

    const bool arow_ok = (bm + r) < LQ;
    const ushort* Ap = A  + (size_t)(bm + r) * 256 + c * 16;
    const ushort* Bp = Bt + (size_t)(bn + r) * 256 + c * 16;

    auto ldA2 = [&](int k0, short8& lo, short8& hi) {
        lo = short8{0,0,0,0,0,0,0,0}; hi = lo;
        if (arow_ok) {
            lo = *reinterpret_cast<const short8*>(Ap + k0);
            hi = *reinterpret_cast<const short8*>(Ap + k0 + 8);
        }
    };

    short8 aLo, aHi, bLo, bHi;
    ldA2(0, aLo, aHi);
    bLo = *reinterpret_cast<const short8*>(Bp);
    bHi = *reinterpret_cast<const short8*>(Bp + 8);
    *reinterpret_cast<short8*>(&As[0][r * LR + c * 16])     = aLo;
    *reinterpret_cast<short8*>(&As[0][r * LR + c * 16 + 8]) = aHi;
    *reinterpret_cast<short8*>(&Bs[0][r * LR + c * 16])     = bLo;
    *reinterpret_cast<short8*>(&Bs[0][r * LR + c * 16 + 8]) = bHi;

    f32x4 acc[4] = {};

    #pragma unroll
    for (int k = 0; k < 4; ++k) {
        __syncthreads();
        if (k < 3) {
            ldA2((k + 1) * 64, aLo, aHi);
            bLo = *reinterpret_cast<const short8*>(Bp + (k + 1) * 64);
            bHi = *reinterpret_cast<const short8*>(Bp + (k + 1) * 64 + 8);
        }
        const int cur = k & 1;
        #pragma unroll
        for (int kh = 0; kh < 2; ++kh) {
            const int ko = kh * 32 + koff;
            const short8 af = *reinterpret_cast<const short8*>(&As[cur][m_l * LR + ko]);
            #pragma unroll
            for (int t = 0; t < 4; ++t) {
                const short8 bf = *reinterpret_cast<const short8*>(
                    &Bs[cur][(t * 16 + lm) * LR + ko]);
                acc[t] = __builtin_amdgcn_mfma_f32_16x16x32_bf16(af, bf, acc[t], 0, 0, 0);
            }
        }
        if (k < 3) {
            const int nxt = cur ^ 1;
            *reinterpret_cast<short8*>(&As[nxt][r * LR + c * 16])     = aLo;
            *reinterpret_cast<short8*>(&As[nxt][r * LR + c * 16 + 8]) = aHi;
            *reinterpret_cast<short8*>(&Bs[nxt][r * LR + c * 16])     = bLo;
            *reinterpret_cast<short8*>(&Bs[nxt][r * LR + c * 16 + 8]) = bHi;
        }
    }

    const int row0 = bm + (w << 4) + ((l >> 4) << 2);
    #pragma unroll
    for (int t = 0; t < 4; ++t) {
        const int col = bn + t * 16 + lm;
        const float bs = bias[col];
        #pragma unroll
        for (int i = 0; i < 4; ++i) {
            const int row = row0 + i;
            if (row < LQ) C[(size_t)row * 256 + col] = acc[t][i] + bs;
        }
    }
}

// ---------------------------------------------------------------------------
// Multi-scale deformable sampling over bf16 value (HEAD-MAJOR [8][LQ][32]).
// Parked at 62 us: rounds 2/4/5 showed {VGPR32,8blk} == {VGPR36,4-5blk} ==
// 62 us (scattered-request-rate/latency equilibrium); manual deep batching
// spills catastrophically. Latency-bound, not occupancy- or VGPR-bound.
// ---------------------------------------------------------------------------
__global__ __launch_bounds__(256, 4) void msda_sample(
    const ushort* __restrict__ v, const float* __restrict__ offattn,
    const float* __restrict__ ref, ushort* __restrict__ outp)
{
    __shared__ int4   s_off[512];   // [p*64 + qi], element offsets within head slice
    __shared__ float4 s_wts[512];

    const int h = blockIdx.x & 7;
    const int qbase = (blockIdx.x >> 3) * 64;
    const int tid = threadIdx.x;

    const int Hs[4] = {100, 50, 25, 13};
    const int Ws[4] = {167, 84, 42, 21};
    const int starts[4] = {0, 16700, 20900, 21950};
    const int h32 = h * 32;

    const int qi = tid >> 2;          // 0..63
    const int dg = tid & 3;           // channel group (8 bf16)
    const int q2 = qbase + qi;
    const int d8 = dg * 8;
    const ushort* vh = v + (size_t)h * ((size_t)LQ * 32) + d8;

    float acc[8] = {};

    #pragma unroll
    for (int half = 0; half < 2; ++half) {
        if (half) __syncthreads();    // protect LDS from previous phase-2 readers

        // ---- Phase 1: 8 points x 64 q = 512 tasks, 2 iterations ----
        #pragma unroll
        for (int t2 = 0; t2 < 2; ++t2) {
            const int t = t2 * 256 + tid;     // = pl*64 + qi
            const int qi1 = t & 63;
            const int pl = t >> 6;            // 0..7
            const int pi = half * 8 + pl;     // 0..15
            const int q = qbase + qi1;
            int4 ob = {0, 0, 0, 0};
            float4 wb = {0.f, 0.f, 0.f, 0.f};
            if (q < LQ) {
                const int l = pi >> 2;
                const int W = Ws[l], H = Hs[l];
                const float* refq = ref + (size_t)q * (NL * 4) + l * 4;
                const float cx = refq[0], cy = refq[1], rw = refq[2], rh = refq[3];
                const float* row = offattn + (size_t)q * 384;
                const float ox  = row[h32 + pi * 2];
                const float oy  = row[h32 + pi * 2 + 1];
                const float wgt = row[256 + h * 16 + pi];

                const float lx = cx + ox * 0.125f * rw;
                const float ly = cy + oy * 0.125f * rh;
                const float x = lx * (float)W - 0.5f;
                const float y = ly * (float)H - 0.5f;

                const float x0f = floorf(x);
                const float y0f = floorf(y);
                const int x0 = (int)x0f, y0 = (int)y0f;
                const float wx1 = x - x0f, wy1 = y - y0f;
                const float wx0 = 1.f - wx1, wy0 = 1.f - wy1;

                const bool xv0 = (x0 >= 0) && (x0 < W);
                const bool xv1 = (x0 + 1 >= 0) && (x0 + 1 < W);
                const bool yv0 = (y0 >= 0) && (y0 < H);
                const bool yv1 = (y0 + 1 >= 0) && (y0 + 1 < H);

                const int x0c = min(max(x0, 0), W - 1);
                const int x1c = min(max(x0 + 1, 0), W - 1);
                const int y0c = min(max(y0, 0), H - 1);
                const int y1c = min(max(y0 + 1, 0), H - 1);

                ob.x = (starts[l] + y0c * W + x0c) * 32;
                ob.y = (starts[l] + y0c * W + x1c) * 32;
                ob.z = (starts[l] + y1c * W + x0c) * 32;
                ob.w = (starts[l] + y1c * W + x1c) * 32;
                wb.x = (xv0 && yv0) ? wgt * wy0 * wx0 : 0.f;
                wb.y = (xv1 && yv0) ? wgt * wy0 * wx1 : 0.f;
                wb.z = (xv0 && yv1) ? wgt * wy1 * wx0 : 0.f;
                wb.w = (xv1 && yv1) ? wgt * wy1 * wx1 : 0.f;
            }
            s_off[t] = ob;
            s_wts[t] = wb;
        }
        __syncthreads();

        // ---- Phase 2: 8 points, unroll 4 ----
        #pragma unroll 4
        for (int p = 0; p < 8; ++p) {
            const int4   o = s_off[p * 64 + qi];
            const float4 w = s_wts[p * 64 + qi];
            const uint4 a0 = *reinterpret_cast<const uint4*>(vh + o.x);
            const uint4 a1 = *reinterpret_cast<const uint4*>(vh + o.y);
            const uint4 a2 = *reinterpret_cast<const uint4*>(vh + o.z);
            const uint4 a3 = *reinterpret_cast<const uint4*>(vh + o.w);
            const unsigned u0[4] = {a0.x, a0.y, a0.z, a0.w};
            const unsigned u1[4] = {a1.x, a1.y, a1.z, a1.w};
            const unsigned u2[4] = {a2.x, a2.y, a2.z, a2.w};
            const unsigned u3[4] = {a3.x, a3.y, a3.z, a3.w};
            #pragma unroll
            for (int j = 0; j < 4; ++j) {
                acc[2 * j]     += w.x * bflo(u0[j]) + w.y * bflo(u1[j])
                                + w.z * bflo(u2[j]) + w.w * bflo(u3[j]);
                acc[2 * j + 1] += w.x * bfhi(u0[j]) + w.y * bfhi(u1[j])
                                + w.z * bfhi(u2[j]) + w.w * bfhi(u3[j]);
            }
        }
    }

    if (q2 < LQ) {
        short8 o8;
        #pragma unroll
        for (int j = 0; j < 8; ++j) o8[j] = (short)f2bf(acc[j]);
        *reinterpret_cast<short8*>(outp + (size_t)q2 * CDIM + h32 + d8) = o8;
    }
}

// ---------------------------------------------------------------------------
extern "C" void kernel_launch(void* const* d_in, const int* in_sizes, int n_in,
                              void* d_out, int out_size, void* d_ws, size_t ws_size,
                              hipStream_t stream)
{
    const float* query  = (const float*)d_in[0];
    const float* ref    = (const float*)d_in[1];
    const float* value  = (const float*)d_in[2];
    const float* W_off  = (const float*)d_in[3];
    const float* b_off  = (const float*)d_in[4];
    const float* W_attn = (const float*)d_in[5];
    const float* b_attn = (const float*)d_in[6];
    const float* W_val  = (const float*)d_in[7];
    const float* b_val  = (const float*)d_in[8];
    const float* W_out  = (const float*)d_in[9];
    const float* b_out  = (const float*)d_in[10];
    float* out = (float*)d_out;

    char* p = (char*)d_ws;
    ushort* v_bf    = (ushort*)p; p += (size_t)LQ * CDIM * 2;   // bf16 value' [8][LQ][32]
    float*  offattn = (float*)p;  p += (size_t)LQ * 384 * 4;
    ushort* outp    = (ushort*)p; p += (size_t)LQ * CDIM * 2;   // bf16 sampled
    ushort* Wt_val  = (ushort*)p; p += 65536 * 2;
    ushort* Wt_oa   = (ushort*)p; p += (65536 + 32768) * 2;
    ushort* Wt_out  = (ushort*)p; p += 65536 * 2;
    float*  bcat    = (float*)p;  p += 384 * 4;

    // 1. weights fp32 -> bf16 [N][K] (+ concatenated off/attn bias)
    convert_wt<<<(229376 + 384 + 255) / 256, 256, 0, stream>>>(
        W_val, W_off, W_out, W_attn, b_off, b_attn, Wt_val, Wt_oa, Wt_out, bcat);

    // 2. fused: v_bf = bf16(value@Wv + bv) [head-major]  AND
    //    offattn = query@Woa + bcat with SOFTMAX fused into the logit tiles
    gemm_dual<<<NBV + NBOA, 256, 0, stream>>>(
        value, Wt_val, b_val, v_bf, query, Wt_oa, bcat, offattn);

    // 3. deformable sampling -> outp (bf16)
    const int qg = (LQ + 63) / 64;    // 348
    msda_sample<<<qg * 8, 256, 0, stream>>>(v_bf, offattn, ref, outp);

    // 4. out = outp @ W_out + b_out
    gemm_out<<<176 * 8, 256, 0, stream>>>(outp, Wt_out, b_out, out);
}

// Round 17
// 196.979 us; speedup vs baseline: 1.0519x; 1.0519x over previous
//
#include <hip/hip_runtime.h>
#include <math.h>

#define LQ 22223
#define NH 8
#define NL 4
#define NP 4
#define CDIM 256
#define MBLK 348              // ceil(LQ/64)
// XCD-swizzled block counts: groups of 8 (one per XCD), 44 row-tiles per XCD
#define NBV  (176 * 8)        // v-GEMM:   4 bx per by  -> j in [0,176)
#define NBOA (264 * 8)        // oa-GEMM:  6 bx per by  -> j in [0,264)

typedef __attribute__((ext_vector_type(8))) short short8;
typedef __attribute__((ext_vector_type(4))) float f32x4;

__device__ __forceinline__ ushort f2bf(float f) {
    union { float f; unsigned u; } c; c.f = f;
    unsigned u = c.u;
    return (ushort)((u + 0x7fffu + ((u >> 16) & 1u)) >> 16);   // RNE
}
__device__ __forceinline__ float bflo(unsigned u) {
    union { unsigned u; float f; } c; c.u = u << 16; return c.f;
}
__device__ __forceinline__ float bfhi(unsigned u) {
    union { unsigned u; float f; } c; c.u = u & 0xffff0000u; return c.f;
}

// ---------------------------------------------------------------------------
// Transpose+convert weights fp32 [K=256][N] -> bf16 [N][K].
// Wt_oa = concat(W_off rows, W_attn rows); bcat = concat(b_off, b_attn).
// ---------------------------------------------------------------------------
__global__ __launch_bounds__(256) void convert_wt(
    const float* __restrict__ Wv, const float* __restrict__ Wo,
    const float* __restrict__ Wu, const float* __restrict__ Wa,
    const float* __restrict__ bo, const float* __restrict__ ba,
    ushort* __restrict__ Tv, ushort* __restrict__ Toa,
    ushort* __restrict__ Tu, float* __restrict__ bcat)
{
    int idx = blockIdx.x * 256 + threadIdx.x;
    if (idx >= 229376) {
        int b = idx - 229376;
        if (b < 384) bcat[b] = (b < 256) ? bo[b] : ba[b - 256];
        return;
    }
    const float* W; ushort* T; int N; int local;
    if      (idx < 65536)  { W = Wv; T = Tv;          N = 256; local = idx; }
    else if (idx < 131072) { W = Wo; T = Toa;         N = 256; local = idx - 65536; }
    else if (idx < 196608) { W = Wu; T = Tu;          N = 256; local = idx - 131072; }
    else                   { W = Wa; T = Toa + 65536; N = 128; local = idx - 196608; }
    int k = local & 255;
    int n = local >> 8;
    T[n * 256 + k] = f2bf(W[k * N + n]);
}

// ---------------------------------------------------------------------------
// Fused dual GEMM, 64x64 tile, XCD-swizzled + LDS double-buffered.
// (BK=32, 5 blocks/CU — best of four GEMM structures measured r5/r9/r12/r16.)
//   blocks [0, NBV):  v_bf = bf16(value @ Wt_val^T + b_val)  head-major out
//   blocks [NBV, ..): query @ Wt_oa^T + bcat, written HEAD-MAJOR:
//     bx<4  -> offsets:  off_hm[h][q][32]  (h=col>>5, ch=col&31)
//     bx>=4 -> softmaxed weights (16-lane __shfl_xor butterfly, verified
//              r11/r15): wts_hm[h][q][16]  (h=(col-256)>>4, ch=lm)
//   Head-major offattn removes the cross-XCD line-sharing in msda (each
//   head-pinned XCD fetched lines it half-used: ~+19 MB FETCH, r16 counters).
// ---------------------------------------------------------------------------
__global__ __launch_bounds__(256, 5) void gemm_dual(
    const float* __restrict__ value, const ushort* __restrict__ Wtv,
    const float* __restrict__ bv, ushort* __restrict__ Cv,
    const float* __restrict__ query, const ushort* __restrict__ Wtoa,
    const float* __restrict__ boa,
    float* __restrict__ off_hm, float* __restrict__ wts_hm)
{
    const int K = 256;
    __shared__ ushort As[2][64 * 40];
    __shared__ ushort Bs[2][64 * 40];

    int b = blockIdx.x;
    const float* A; const ushort* Bt; const float* bias;
    int bx, by; bool isv;
    const int xcd = b & 7;
    if (b < NBV) {
        isv = true;  A = value; Bt = Wtv;  bias = bv;
        const int j = b >> 3;
        bx = j & 3;  by = xcd + 8 * (j >> 2);
    } else {
        isv = false; A = query; Bt = Wtoa; bias = boa;
        const int j = (b - NBV) >> 3;
        bx = j % 6;  by = xcd + 8 * (j / 6);
    }
    if (by >= MBLK) return;

    const int tid = threadIdx.x;
    const int w = tid >> 6;
    const int l = tid & 63;
    const int bm = by * 64;
    const int bn = bx * 64;

    const int r = tid >> 2;
    const int c = tid & 3;

    const int m_l  = (w << 4) + (l & 15);
    const int koff = (l >> 4) << 3;

    const bool arow_ok = (bm + r) < LQ;
    const float*  Ap = A  + (size_t)(bm + r) * K + c * 8;
    const ushort* Bp = Bt + (size_t)(bn + r) * K + c * 8;

    auto ldA = [&](int k0) -> short8 {
        short8 av = {0, 0, 0, 0, 0, 0, 0, 0};
        if (arow_ok) {
            const float4 f0 = *reinterpret_cast<const float4*>(Ap + k0);
            const float4 f1 = *reinterpret_cast<const float4*>(Ap + k0 + 4);
            av[0] = (short)f2bf(f0.x); av[1] = (short)f2bf(f0.y);
            av[2] = (short)f2bf(f0.z); av[3] = (short)f2bf(f0.w);
            av[4] = (short)f2bf(f1.x); av[5] = (short)f2bf(f1.y);
            av[6] = (short)f2bf(f1.z); av[7] = (short)f2bf(f1.w);
        }
        return av;
    };

    short8 av = ldA(0);
    short8 bvv = *reinterpret_cast<const short8*>(Bp);
    *reinterpret_cast<short8*>(&As[0][r * 40 + c * 8]) = av;
    *reinterpret_cast<short8*>(&Bs[0][r * 40 + c * 8]) = bvv;

    f32x4 acc[4] = {};

    #pragma unroll
    for (int k = 0; k < 8; ++k) {
        __syncthreads();
        if (k < 7) {
            av  = ldA((k + 1) * 32);
            bvv = *reinterpret_cast<const short8*>(Bp + (k + 1) * 32);
        }
        const int cur = k & 1;
        const short8 af = *reinterpret_cast<const short8*>(&As[cur][m_l * 40 + koff]);
        #pragma unroll
        for (int t = 0; t < 4; ++t) {
            const short8 bf = *reinterpret_cast<const short8*>(
                &Bs[cur][(t * 16 + (l & 15)) * 40 + koff]);
            acc[t] = __builtin_amdgcn_mfma_f32_16x16x32_bf16(af, bf, acc[t], 0, 0, 0);
        }
        if (k < 7) {
            const int nxt = cur ^ 1;
            *reinterpret_cast<short8*>(&As[nxt][r * 40 + c * 8]) = av;
            *reinterpret_cast<short8*>(&Bs[nxt][r * 40 + c * 8]) = bvv;
        }
    }

    const int row0 = bm + (w << 4) + ((l >> 4) << 2);
    const int lm = l & 15;

    if (!isv && bx >= 4) {
        // ---- fused softmax epilogue -> wts_hm[h][q][16] ----
        #pragma unroll
        for (int t = 0; t < 4; ++t) {
            const int col = bn + t * 16 + lm;
            const float bs = bias[col];
            const int head = (col - 256) >> 4;      // 16-aligned groups: lm = ch
            #pragma unroll
            for (int i = 0; i < 4; ++i) {
                const int row = row0 + i;
                const float L = acc[t][i] + bs;
                float mx = L;
                #pragma unroll
                for (int s = 1; s < 16; s <<= 1)
                    mx = fmaxf(mx, __shfl_xor(mx, s));
                const float e = expf(L - mx);
                float sum = e;
                #pragma unroll
                for (int s = 1; s < 16; s <<= 1)
                    sum += __shfl_xor(sum, s);
                if (row < LQ)
                    wts_hm[(size_t)head * ((size_t)LQ * 16) + (size_t)row * 16 + lm] = e / sum;
            }
        }
    } else {
        #pragma unroll
        for (int t = 0; t < 4; ++t) {
            const int col = bn + t * 16 + lm;
            const float bs = bias[col];
            #pragma unroll
            for (int i = 0; i < 4; ++i) {
                const int row = row0 + i;
                if (row < LQ) {
                    const float o = acc[t][i] + bs;
                    if (isv) {
                        // head-major: [h][row][ch32]
                        const int head = col >> 5;
                        const int ch   = col & 31;
                        Cv[(size_t)head * ((size_t)LQ * 32) + (size_t)row * 32 + ch] = f2bf(o);
                    } else {
                        // offsets head-major: off_hm[h][row][ch32]
                        const int head = col >> 5;
                        const int ch   = col & 31;
                        off_hm[(size_t)head * ((size_t)LQ * 32) + (size_t)row * 32 + ch] = o;
                    }
                }
            }
        }
    }
}

// ---------------------------------------------------------------------------
// Output GEMM (bf16 A), same swizzle + double buffer. N=256, fp32 out.
// ---------------------------------------------------------------------------
__global__ __launch_bounds__(256, 5) void gemm_out(
    const ushort* __restrict__ A, const ushort* __restrict__ Bt,
    const float* __restrict__ bias, float* __restrict__ C)
{
    const int K = 256, N = 256;
    __shared__ ushort As[2][64 * 40];
    __shared__ ushort Bs[2][64 * 40];

    const int b = blockIdx.x;
    const int xcd = b & 7;
    const int j = b >> 3;
    const int bx = j & 3;
    const int by = xcd + 8 * (j >> 2);
    if (by >= MBLK) return;

    const int tid = threadIdx.x;
    const int w = tid >> 6;
    const int l = tid & 63;
    const int bm = by * 64;
    const int bn = bx * 64;

    const int r = tid >> 2;
    const int c = tid & 3;

    const int m_l  = (w << 4) + (l & 15);
    const int koff = (l >> 4) << 3;

    const bool arow_ok = (bm + r) < LQ;
    const ushort* Ap = A  + (size_t)(bm + r) * K + c * 8;
    const ushort* Bp = Bt + (size_t)(bn + r) * K + c * 8;

    auto ldA = [&](int k0) -> short8 {
        short8 av = {0, 0, 0, 0, 0, 0, 0, 0};
        if (arow_ok) av = *reinterpret_cast<const short8*>(Ap + k0);
        return av;
    };

    short8 av = ldA(0);
    short8 bvv = *reinterpret_cast<const short8*>(Bp);
    *reinterpret_cast<short8*>(&As[0][r * 40 + c * 8]) = av;
    *reinterpret_cast<short8*>(&Bs[0][r * 40 + c * 8]) = bvv;

    f32x4 acc[4] = {};

    #pragma unroll
    for (int k = 0; k < 8; ++k) {
        __syncthreads();
        if (k < 7) {
            av  = ldA((k + 1) * 32);
            bvv = *reinterpret_cast<const short8*>(Bp + (k + 1) * 32);
        }
        const int cur = k & 1;
        const short8 af = *reinterpret_cast<const short8*>(&As[cur][m_l * 40 + koff]);
        #pragma unroll
        for (int t = 0; t < 4; ++t) {
            const short8 bf = *reinterpret_cast<const short8*>(
                &Bs[cur][(t * 16 + (l & 15)) * 40 + koff]);
            acc[t] = __builtin_amdgcn_mfma_f32_16x16x32_bf16(af, bf, acc[t], 0, 0, 0);
        }
        if (k < 7) {
            const int nxt = cur ^ 1;
            *reinterpret_cast<short8*>(&As[nxt][r * 40 + c * 8]) = av;
            *reinterpret_cast<short8*>(&Bs[nxt][r * 40 + c * 8]) = bvv;
        }
    }

    const int row0 = bm + (w << 4) + ((l >> 4) << 2);
    #pragma unroll
    for (int t = 0; t < 4; ++t) {
        const int col = bn + t * 16 + (l & 15);
        const float bs = bias[col];
        #pragma unroll
        for (int i = 0; i < 4; ++i) {
            const int row = row0 + i;
            if (row < LQ) C[(size_t)row * N + col] = acc[t][i] + bs;
        }
    }
}

// ---------------------------------------------------------------------------
// Multi-scale deformable sampling over bf16 value (HEAD-MAJOR [8][LQ][32]).
// Offsets/weights now ALSO head-major (off_hm[8][LQ][32], wts_hm[8][LQ][16])
// -> each (q,h) read is contiguous + XCD-local; removes cross-XCD line
// duplication (~19 MB of the 66 MB FETCH in r16).
// Parked structure: rounds 2/4/5 showed the gather loop is latency-bound;
// occupancy/VGPR knobs don't move it, manual deep batching spills.
// ---------------------------------------------------------------------------
__global__ __launch_bounds__(256, 4) void msda_sample(
    const ushort* __restrict__ v, const float* __restrict__ off_hm,
    const float* __restrict__ wts_hm, const float* __restrict__ ref,
    ushort* __restrict__ outp)
{
    __shared__ int4   s_off[512];   // [p*64 + qi], element offsets within head slice
    __shared__ float4 s_wts[512];

    const int h = blockIdx.x & 7;
    const int qbase = (blockIdx.x >> 3) * 64;
    const int tid = threadIdx.x;

    const int Hs[4] = {100, 50, 25, 13};
    const int Ws[4] = {167, 84, 42, 21};
    const int starts[4] = {0, 16700, 20900, 21950};
    const int h32 = h * 32;

    const int qi = tid >> 2;          // 0..63
    const int dg = tid & 3;           // channel group (8 bf16)
    const int q2 = qbase + qi;
    const int d8 = dg * 8;
    const ushort* vh = v + (size_t)h * ((size_t)LQ * 32) + d8;
    const float* offh = off_hm + (size_t)h * ((size_t)LQ * 32);
    const float* wtsh = wts_hm + (size_t)h * ((size_t)LQ * 16);

    float acc[8] = {};

    #pragma unroll
    for (int half = 0; half < 2; ++half) {
        if (half) __syncthreads();    // protect LDS from previous phase-2 readers

        // ---- Phase 1: 8 points x 64 q = 512 tasks, 2 iterations ----
        #pragma unroll
        for (int t2 = 0; t2 < 2; ++t2) {
            const int t = t2 * 256 + tid;     // = pl*64 + qi
            const int qi1 = t & 63;
            const int pl = t >> 6;            // 0..7
            const int pi = half * 8 + pl;     // 0..15
            const int q = qbase + qi1;
            int4 ob = {0, 0, 0, 0};
            float4 wb = {0.f, 0.f, 0.f, 0.f};
            if (q < LQ) {
                const int l = pi >> 2;
                const int W = Ws[l], H = Hs[l];
                const float* refq = ref + (size_t)q * (NL * 4) + l * 4;
                const float cx = refq[0], cy = refq[1], rw = refq[2], rh = refq[3];
                const float ox  = offh[(size_t)q * 32 + pi * 2];
                const float oy  = offh[(size_t)q * 32 + pi * 2 + 1];
                const float wgt = wtsh[(size_t)q * 16 + pi];

                const float lx = cx + ox * 0.125f * rw;
                const float ly = cy + oy * 0.125f * rh;
                const float x = lx * (float)W - 0.5f;
                const float y = ly * (float)H - 0.5f;

                const float x0f = floorf(x);
                const float y0f = floorf(y);
                const int x0 = (int)x0f, y0 = (int)y0f;
                const float wx1 = x - x0f, wy1 = y - y0f;
                const float wx0 = 1.f - wx1, wy0 = 1.f - wy1;

                const bool xv0 = (x0 >= 0) && (x0 < W);
                const bool xv1 = (x0 + 1 >= 0) && (x0 + 1 < W);
                const bool yv0 = (y0 >= 0) && (y0 < H);
                const bool yv1 = (y0 + 1 >= 0) && (y0 + 1 < H);

                const int x0c = min(max(x0, 0), W - 1);
                const int x1c = min(max(x0 + 1, 0), W - 1);
                const int y0c = min(max(y0, 0), H - 1);
                const int y1c = min(max(y0 + 1, 0), H - 1);

                ob.x = (starts[l] + y0c * W + x0c) * 32;
                ob.y = (starts[l] + y0c * W + x1c) * 32;
                ob.z = (starts[l] + y1c * W + x0c) * 32;
                ob.w = (starts[l] + y1c * W + x1c) * 32;
                wb.x = (xv0 && yv0) ? wgt * wy0 * wx0 : 0.f;
                wb.y = (xv1 && yv0) ? wgt * wy0 * wx1 : 0.f;
                wb.z = (xv0 && yv1) ? wgt * wy1 * wx0 : 0.f;
                wb.w = (xv1 && yv1) ? wgt * wy1 * wx1 : 0.f;
            }
            s_off[t] = ob;
            s_wts[t] = wb;
        }
        __syncthreads();

        // ---- Phase 2: 8 points, unroll 4 ----
        #pragma unroll 4
        for (int p = 0; p < 8; ++p) {
            const int4   o = s_off[p * 64 + qi];
            const float4 w = s_wts[p * 64 + qi];
            const uint4 a0 = *reinterpret_cast<const uint4*>(vh + o.x);
            const uint4 a1 = *reinterpret_cast<const uint4*>(vh + o.y);
            const uint4 a2 = *reinterpret_cast<const uint4*>(vh + o.z);
            const uint4 a3 = *reinterpret_cast<const uint4*>(vh + o.w);
            const unsigned u0[4] = {a0.x, a0.y, a0.z, a0.w};
            const unsigned u1[4] = {a1.x, a1.y, a1.z, a1.w};
            const unsigned u2[4] = {a2.x, a2.y, a2.z, a2.w};
            const unsigned u3[4] = {a3.x, a3.y, a3.z, a3.w};
            #pragma unroll
            for (int j = 0; j < 4; ++j) {
                acc[2 * j]     += w.x * bflo(u0[j]) + w.y * bflo(u1[j])
                                + w.z * bflo(u2[j]) + w.w * bflo(u3[j]);
                acc[2 * j + 1] += w.x * bfhi(u0[j]) + w.y * bfhi(u1[j])
                                + w.z * bfhi(u2[j]) + w.w * bfhi(u3[j]);
            }
        }
    }

    if (q2 < LQ) {
        short8 o8;
        #pragma unroll
        for (int j = 0; j < 8; ++j) o8[j] = (short)f2bf(acc[j]);
        *reinterpret_cast<short8*>(outp + (size_t)q2 * CDIM + h32 + d8) = o8;
    }
}

// ---------------------------------------------------------------------------
extern "C" void kernel_launch(void* const* d_in, const int* in_sizes, int n_in,
                              void* d_out, int out_size, void* d_ws, size_t ws_size,
                              hipStream_t stream)
{
    const float* query  = (const float*)d_in[0];
    const float* ref    = (const float*)d_in[1];
    const float* value  = (const float*)d_in[2];
    const float* W_off  = (const float*)d_in[3];
    const float* b_off  = (const float*)d_in[4];
    const float* W_attn = (const float*)d_in[5];
    const float* b_attn = (const float*)d_in[6];
    const float* W_val  = (const float*)d_in[7];
    const float* b_val  = (const float*)d_in[8];
    const float* W_out  = (const float*)d_in[9];
    const float* b_out  = (const float*)d_in[10];
    float* out = (float*)d_out;

    char* p = (char*)d_ws;
    ushort* v_bf    = (ushort*)p; p += (size_t)LQ * CDIM * 2;   // bf16 value' [8][LQ][32]
    float*  off_hm  = (float*)p;  p += (size_t)LQ * 256 * 4;    // offsets [8][LQ][32]
    float*  wts_hm  = (float*)p;  p += (size_t)LQ * 128 * 4;    // weights [8][LQ][16]
    ushort* outp    = (ushort*)p; p += (size_t)LQ * CDIM * 2;   // bf16 sampled
    ushort* Wt_val  = (ushort*)p; p += 65536 * 2;
    ushort* Wt_oa   = (ushort*)p; p += (65536 + 32768) * 2;
    ushort* Wt_out  = (ushort*)p; p += 65536 * 2;
    float*  bcat    = (float*)p;  p += 384 * 4;

    // 1. weights fp32 -> bf16 [N][K] (+ concatenated off/attn bias)
    convert_wt<<<(229376 + 384 + 255) / 256, 256, 0, stream>>>(
        W_val, W_off, W_out, W_attn, b_off, b_attn, Wt_val, Wt_oa, Wt_out, bcat);

    // 2. fused: v_bf = bf16(value@Wv + bv) [head-major]  AND
    //    offsets/softmaxed-weights head-major (softmax fused)
    gemm_dual<<<NBV + NBOA, 256, 0, stream>>>(
        value, Wt_val, b_val, v_bf, query, Wt_oa, bcat, off_hm, wts_hm);

    // 3. deformable sampling -> outp (bf16)
    const int qg = (LQ + 63) / 64;    // 348
    msda_sample<<<qg * 8, 256, 0, stream>>>(v_bf, off_hm, wts_hm, ref, outp);

    // 4. out = outp @ W_out + b_out
    gemm_out<<<176 * 8, 256, 0, stream>>>(outp, Wt_out, b_out, out);
}

// Round 19
// 190.169 us; speedup vs baseline: 1.0896x; 1.0358x over previous
//
#include <hip/hip_runtime.h>
#include <math.h>

#define LQ 22223
#define NH 8
#define NL 4
#define NP 4
#define CDIM 256
#define MBLK 348              // ceil(LQ/64)
// XCD-swizzled block counts: groups of 8 (one per XCD), 44 row-tiles per XCD
#define NBV  (176 * 8)        // v-GEMM:   4 bx per by  -> j in [0,176)
#define NBOA (264 * 8)        // oa-GEMM:  6 bx per by  -> j in [0,264)

typedef __attribute__((ext_vector_type(8))) short short8;
typedef __attribute__((ext_vector_type(4))) float f32x4;

__device__ __forceinline__ ushort f2bf(float f) {
    union { float f; unsigned u; } c; c.f = f;
    unsigned u = c.u;
    return (ushort)((u + 0x7fffu + ((u >> 16) & 1u)) >> 16);   // RNE
}
__device__ __forceinline__ float bflo(unsigned u) {
    union { unsigned u; float f; } c; c.u = u << 16; return c.f;
}
__device__ __forceinline__ float bfhi(unsigned u) {
    union { unsigned u; float f; } c; c.u = u & 0xffff0000u; return c.f;
}

// ---------------------------------------------------------------------------
// Transpose+convert weights fp32 [K=256][N] -> bf16 [N][K].
// Wt_oa = concat(W_off rows, W_attn rows); bcat = concat(b_off, b_attn).
// ---------------------------------------------------------------------------
__global__ __launch_bounds__(256) void convert_wt(
    const float* __restrict__ Wv, const float* __restrict__ Wo,
    const float* __restrict__ Wu, const float* __restrict__ Wa,
    const float* __restrict__ bo, const float* __restrict__ ba,
    ushort* __restrict__ Tv, ushort* __restrict__ Toa,
    ushort* __restrict__ Tu, float* __restrict__ bcat)
{
    int idx = blockIdx.x * 256 + threadIdx.x;
    if (idx >= 229376) {
        int b = idx - 229376;
        if (b < 384) bcat[b] = (b < 256) ? bo[b] : ba[b - 256];
        return;
    }
    const float* W; ushort* T; int N; int local;
    if      (idx < 65536)  { W = Wv; T = Tv;          N = 256; local = idx; }
    else if (idx < 131072) { W = Wo; T = Toa;         N = 256; local = idx - 65536; }
    else if (idx < 196608) { W = Wu; T = Tu;          N = 256; local = idx - 131072; }
    else                   { W = Wa; T = Toa + 65536; N = 128; local = idx - 196608; }
    int k = local & 255;
    int n = local >> 8;
    T[n * 256 + k] = f2bf(W[k * N + n]);
}

// ---------------------------------------------------------------------------
// Fused dual GEMM, 64x64 tile, XCD-swizzled + LDS double-buffered.
// (BK=32, 5 blocks/CU — best of four GEMM structures measured r5/r9/r12/r16.)
//   blocks [0, NBV):  v_bf = bf16(value @ Wt_val^T + b_val)  head-major out
//   blocks [NBV, ..): query @ Wt_oa^T + bcat, written HEAD-MAJOR:
//     bx<4  -> FINAL SAMPLE COORDS: off_hm[h][q][32] = (cxy + o*0.125*scl)
//              * dim - 0.5 — ref folded in here (L2-hot, XCD-local; lanes of
//              a 16-group share the row -> 1-2 lines per group). msda then
//              needs NO ref read (saves 11.4 MB cross-XCD re-fetch, r17).
//     bx>=4 -> softmaxed weights (16-lane __shfl_xor butterfly, verified
//              r11/r15): wts_hm[h][q][16]
// ---------------------------------------------------------------------------
__global__ __launch_bounds__(256, 5) void gemm_dual(
    const float* __restrict__ value, const ushort* __restrict__ Wtv,
    const float* __restrict__ bv, ushort* __restrict__ Cv,
    const float* __restrict__ query, const ushort* __restrict__ Wtoa,
    const float* __restrict__ boa, const float* __restrict__ ref,
    float* __restrict__ off_hm, float* __restrict__ wts_hm)
{
    const int K = 256;
    __shared__ ushort As[2][64 * 40];
    __shared__ ushort Bs[2][64 * 40];

    int b = blockIdx.x;
    const float* A; const ushort* Bt; const float* bias;
    int bx, by; bool isv;
    const int xcd = b & 7;
    if (b < NBV) {
        isv = true;  A = value; Bt = Wtv;  bias = bv;
        const int j = b >> 3;
        bx = j & 3;  by = xcd + 8 * (j >> 2);
    } else {
        isv = false; A = query; Bt = Wtoa; bias = boa;
        const int j = (b - NBV) >> 3;
        bx = j % 6;  by = xcd + 8 * (j / 6);
    }
    if (by >= MBLK) return;

    const int tid = threadIdx.x;
    const int w = tid >> 6;
    const int l = tid & 63;
    const int bm = by * 64;
    const int bn = bx * 64;

    const int r = tid >> 2;
    const int c = tid & 3;

    const int m_l  = (w << 4) + (l & 15);
    const int koff = (l >> 4) << 3;

    const bool arow_ok = (bm + r) < LQ;
    const float*  Ap = A  + (size_t)(bm + r) * K + c * 8;
    const ushort* Bp = Bt + (size_t)(bn + r) * K + c * 8;

    auto ldA = [&](int k0) -> short8 {
        short8 av = {0, 0, 0, 0, 0, 0, 0, 0};
        if (arow_ok) {
            const float4 f0 = *reinterpret_cast<const float4*>(Ap + k0);
            const float4 f1 = *reinterpret_cast<const float4*>(Ap + k0 + 4);
            av[0] = (short)f2bf(f0.x); av[1] = (short)f2bf(f0.y);
            av[2] = (short)f2bf(f0.z); av[3] = (short)f2bf(f0.w);
            av[4] = (short)f2bf(f1.x); av[5] = (short)f2bf(f1.y);
            av[6] = (short)f2bf(f1.z); av[7] = (short)f2bf(f1.w);
        }
        return av;
    };

    short8 av = ldA(0);
    short8 bvv = *reinterpret_cast<const short8*>(Bp);
    *reinterpret_cast<short8*>(&As[0][r * 40 + c * 8]) = av;
    *reinterpret_cast<short8*>(&Bs[0][r * 40 + c * 8]) = bvv;

    f32x4 acc[4] = {};

    #pragma unroll
    for (int k = 0; k < 8; ++k) {
        __syncthreads();
        if (k < 7) {
            av  = ldA((k + 1) * 32);
            bvv = *reinterpret_cast<const short8*>(Bp + (k + 1) * 32);
        }
        const int cur = k & 1;
        const short8 af = *reinterpret_cast<const short8*>(&As[cur][m_l * 40 + koff]);
        #pragma unroll
        for (int t = 0; t < 4; ++t) {
            const short8 bf = *reinterpret_cast<const short8*>(
                &Bs[cur][(t * 16 + (l & 15)) * 40 + koff]);
            acc[t] = __builtin_amdgcn_mfma_f32_16x16x32_bf16(af, bf, acc[t], 0, 0, 0);
        }
        if (k < 7) {
            const int nxt = cur ^ 1;
            *reinterpret_cast<short8*>(&As[nxt][r * 40 + c * 8]) = av;
            *reinterpret_cast<short8*>(&Bs[nxt][r * 40 + c * 8]) = bvv;
        }
    }

    const int row0 = bm + (w << 4) + ((l >> 4) << 2);
    const int lm = l & 15;

    if (!isv && bx >= 4) {
        // ---- fused softmax epilogue -> wts_hm[h][q][16] ----
        #pragma unroll
        for (int t = 0; t < 4; ++t) {
            const int col = bn + t * 16 + lm;
            const float bs = bias[col];
            const int head = (col - 256) >> 4;      // 16-aligned groups: lm = ch
            #pragma unroll
            for (int i = 0; i < 4; ++i) {
                const int row = row0 + i;
                const float L = acc[t][i] + bs;
                float mx = L;
                #pragma unroll
                for (int s = 1; s < 16; s <<= 1)
                    mx = fmaxf(mx, __shfl_xor(mx, s));
                const float e = expf(L - mx);
                float sum = e;
                #pragma unroll
                for (int s = 1; s < 16; s <<= 1)
                    sum += __shfl_xor(sum, s);
                if (row < LQ)
                    wts_hm[(size_t)head * ((size_t)LQ * 16) + (size_t)row * 16 + lm] = e / sum;
            }
        }
    } else if (!isv) {
        // ---- offset epilogue with ref folded in -> FINAL coords ----
        const float DIMW[4] = {167.f, 84.f, 42.f, 21.f};
        const float DIMH[4] = {100.f, 50.f, 25.f, 13.f};
        #pragma unroll
        for (int t = 0; t < 4; ++t) {
            const int col  = bn + t * 16 + lm;
            const float bs = bias[col];
            const int ch    = col & 31;
            const int head  = col >> 5;
            const int level = ch >> 3;
            const int xy    = ch & 1;
            const float dim = xy ? DIMH[level] : DIMW[level];
            #pragma unroll
            for (int i = 0; i < 4; ++i) {
                const int row = row0 + i;
                if (row < LQ) {
                    const float o   = acc[t][i] + bs;
                    const float cxy = ref[(size_t)row * 16 + level * 4 + xy];
                    const float scl = ref[(size_t)row * 16 + level * 4 + 2 + xy];
                    // identical op order to the previous msda phase-1:
                    // l = cxy + o*0.125*scl;  coord = l*dim - 0.5
                    const float lcoord = cxy + o * 0.125f * scl;
                    off_hm[(size_t)head * ((size_t)LQ * 32) + (size_t)row * 32 + ch]
                        = lcoord * dim - 0.5f;
                }
            }
        }
    } else {
        #pragma unroll
        for (int t = 0; t < 4; ++t) {
            const int col = bn + t * 16 + lm;
            const float bs = bias[col];
            #pragma unroll
            for (int i = 0; i < 4; ++i) {
                const int row = row0 + i;
                if (row < LQ) {
                    const float o = acc[t][i] + bs;
                    // head-major: [h][row][ch32]
                    const int head = col >> 5;
                    const int ch   = col & 31;
                    Cv[(size_t)head * ((size_t)LQ * 32) + (size_t)row * 32 + ch] = f2bf(o);
                }
            }
        }
    }
}

// ---------------------------------------------------------------------------
// Output GEMM (bf16 A), same swizzle + double buffer. N=256, fp32 out.
// ---------------------------------------------------------------------------
__global__ __launch_bounds__(256, 5) void gemm_out(
    const ushort* __restrict__ A, const ushort* __restrict__ Bt,
    const float* __restrict__ bias, float* __restrict__ C)
{
    const int K = 256, N = 256;
    __shared__ ushort As[2][64 * 40];
    __shared__ ushort Bs[2][64 * 40];

    const int b = blockIdx.x;
    const int xcd = b & 7;
    const int j = b >> 3;
    const int bx = j & 3;
    const int by = xcd + 8 * (j >> 2);
    if (by >= MBLK) return;

    const int tid = threadIdx.x;
    const int w = tid >> 6;
    const int l = tid & 63;
    const int bm = by * 64;
    const int bn = bx * 64;

    const int r = tid >> 2;
    const int c = tid & 3;

    const int m_l  = (w << 4) + (l & 15);
    const int koff = (l >> 4) << 3;

    const bool arow_ok = (bm + r) < LQ;
    const ushort* Ap = A  + (size_t)(bm + r) * K + c * 8;
    const ushort* Bp = Bt + (size_t)(bn + r) * K + c * 8;

    auto ldA = [&](int k0) -> short8 {
        short8 av = {0, 0, 0, 0, 0, 0, 0, 0};
        if (arow_ok) av = *reinterpret_cast<const short8*>(Ap + k0);
        return av;
    };

    short8 av = ldA(0);
    short8 bvv = *reinterpret_cast<const short8*>(Bp);
    *reinterpret_cast<short8*>(&As[0][r * 40 + c * 8]) = av;
    *reinterpret_cast<short8*>(&Bs[0][r * 40 + c * 8]) = bvv;

    f32x4 acc[4] = {};

    #pragma unroll
    for (int k = 0; k < 8; ++k) {
        __syncthreads();
        if (k < 7) {
            av  = ldA((k + 1) * 32);
            bvv = *reinterpret_cast<const short8*>(Bp + (k + 1) * 32);
        }
        const int cur = k & 1;
        const short8 af = *reinterpret_cast<const short8*>(&As[cur][m_l * 40 + koff]);
        #pragma unroll
        for (int t = 0; t < 4; ++t) {
            const short8 bf = *reinterpret_cast<const short8*>(
                &Bs[cur][(t * 16 + (l & 15)) * 40 + koff]);
            acc[t] = __builtin_amdgcn_mfma_f32_16x16x32_bf16(af, bf, acc[t], 0, 0, 0);
        }
        if (k < 7) {
            const int nxt = cur ^ 1;
            *reinterpret_cast<short8*>(&As[nxt][r * 40 + c * 8]) = av;
            *reinterpret_cast<short8*>(&Bs[nxt][r * 40 + c * 8]) = bvv;
        }
    }

    const int row0 = bm + (w << 4) + ((l >> 4) << 2);
    #pragma unroll
    for (int t = 0; t < 4; ++t) {
        const int col = bn + t * 16 + (l & 15);
        const float bs = bias[col];
        #pragma unroll
        for (int i = 0; i < 4; ++i) {
            const int row = row0 + i;
            if (row < LQ) C[(size_t)row * N + col] = acc[t][i] + bs;
        }
    }
}

// ---------------------------------------------------------------------------
// Multi-scale deformable sampling over bf16 value (HEAD-MAJOR [8][LQ][32]).
// off_hm now holds FINAL sample coords (ref folded into gemm_dual) ->
// phase 1 is just floor/clamp/bilinear-weights; no ref fetch at all.
// Parked structure: rounds 2/4/5 showed the gather loop is latency-bound.
// ---------------------------------------------------------------------------
__global__ __launch_bounds__(256, 4) void msda_sample(
    const ushort* __restrict__ v, const float* __restrict__ off_hm,
    const float* __restrict__ wts_hm, ushort* __restrict__ outp)
{
    __shared__ int4   s_off[512];   // [p*64 + qi], element offsets within head slice
    __shared__ float4 s_wts[512];

    const int h = blockIdx.x & 7;
    const int qbase = (blockIdx.x >> 3) * 64;
    const int tid = threadIdx.x;

    const int Hs[4] = {100, 50, 25, 13};
    const int Ws[4] = {167, 84, 42, 21};
    const int starts[4] = {0, 16700, 20900, 21950};
    const int h32 = h * 32;

    const int qi = tid >> 2;          // 0..63
    const int dg = tid & 3;           // channel group (8 bf16)
    const int q2 = qbase + qi;
    const int d8 = dg * 8;
    const ushort* vh = v + (size_t)h * ((size_t)LQ * 32) + d8;
    const float* offh = off_hm + (size_t)h * ((size_t)LQ * 32);
    const float* wtsh = wts_hm + (size_t)h * ((size_t)LQ * 16);

    float acc[8] = {};

    #pragma unroll
    for (int half = 0; half < 2; ++half) {
        if (half) __syncthreads();    // protect LDS from previous phase-2 readers

        // ---- Phase 1: 8 points x 64 q = 512 tasks, 2 iterations ----
        #pragma unroll
        for (int t2 = 0; t2 < 2; ++t2) {
            const int t = t2 * 256 + tid;     // = pl*64 + qi
            const int qi1 = t & 63;
            const int pl = t >> 6;            // 0..7
            const int pi = half * 8 + pl;     // 0..15
            const int q = qbase + qi1;
            int4 ob = {0, 0, 0, 0};
            float4 wb = {0.f, 0.f, 0.f, 0.f};
            if (q < LQ) {
                const int l = pi >> 2;
                const int W = Ws[l], H = Hs[l];
                const float x   = offh[(size_t)q * 32 + pi * 2];      // final coord
                const float y   = offh[(size_t)q * 32 + pi * 2 + 1];
                const float wgt = wtsh[(size_t)q * 16 + pi];

                const float x0f = floorf(x);
                const float y0f = floorf(y);
                const int x0 = (int)x0f, y0 = (int)y0f;
                const float wx1 = x - x0f, wy1 = y - y0f;
                const float wx0 = 1.f - wx1, wy0 = 1.f - wy1;

                const bool xv0 = (x0 >= 0) && (x0 < W);
                const bool xv1 = (x0 + 1 >= 0) && (x0 + 1 < W);
                const bool yv0 = (y0 >= 0) && (y0 < H);
                const bool yv1 = (y0 + 1 >= 0) && (y0 + 1 < H);

                const int x0c = min(max(x0, 0), W - 1);
                const int x1c = min(max(x0 + 1, 0), W - 1);
                const int y0c = min(max(y0, 0), H - 1);
                const int y1c = min(max(y0 + 1, 0), H - 1);

                ob.x = (starts[l] + y0c * W + x0c) * 32;
                ob.y = (starts[l] + y0c * W + x1c) * 32;
                ob.z = (starts[l] + y1c * W + x0c) * 32;
                ob.w = (starts[l] + y1c * W + x1c) * 32;
                wb.x = (xv0 && yv0) ? wgt * wy0 * wx0 : 0.f;
                wb.y = (xv1 && yv0) ? wgt * wy0 * wx1 : 0.f;
                wb.z = (xv0 && yv1) ? wgt * wy1 * wx0 : 0.f;
                wb.w = (xv1 && yv1) ? wgt * wy1 * wx1 : 0.f;
            }
            s_off[t] = ob;
            s_wts[t] = wb;
        }
        __syncthreads();

        // ---- Phase 2: 8 points, unroll 4 ----
        #pragma unroll 4
        for (int p = 0; p < 8; ++p) {
            const int4   o = s_off[p * 64 + qi];
            const float4 w = s_wts[p * 64 + qi];
            const uint4 a0 = *reinterpret_cast<const uint4*>(vh + o.x);
            const uint4 a1 = *reinterpret_cast<const uint4*>(vh + o.y);
            const uint4 a2 = *reinterpret_cast<const uint4*>(vh + o.z);
            const uint4 a3 = *reinterpret_cast<const uint4*>(vh + o.w);
            const unsigned u0[4] = {a0.x, a0.y, a0.z, a0.w};
            const unsigned u1[4] = {a1.x, a1.y, a1.z, a1.w};
            const unsigned u2[4] = {a2.x, a2.y, a2.z, a2.w};
            const unsigned u3[4] = {a3.x, a3.y, a3.z, a3.w};
            #pragma unroll
            for (int j = 0; j < 4; ++j) {
                acc[2 * j]     += w.x * bflo(u0[j]) + w.y * bflo(u1[j])
                                + w.z * bflo(u2[j]) + w.w * bflo(u3[j]);
                acc[2 * j + 1] += w.x * bfhi(u0[j]) + w.y * bfhi(u1[j])
                                + w.z * bfhi(u2[j]) + w.w * bfhi(u3[j]);
            }
        }
    }

    if (q2 < LQ) {
        short8 o8;
        #pragma unroll
        for (int j = 0; j < 8; ++j) o8[j] = (short)f2bf(acc[j]);
        *reinterpret_cast<short8*>(outp + (size_t)q2 * CDIM + h32 + d8) = o8;
    }
}

// ---------------------------------------------------------------------------
extern "C" void kernel_launch(void* const* d_in, const int* in_sizes, int n_in,
                              void* d_out, int out_size, void* d_ws, size_t ws_size,
                              hipStream_t stream)
{
    const float* query  = (const float*)d_in[0];
    const float* ref    = (const float*)d_in[1];
    const float* value  = (const float*)d_in[2];
    const float* W_off  = (const float*)d_in[3];
    const float* b_off  = (const float*)d_in[4];
    const float* W_attn = (const float*)d_in[5];
    const float* b_attn = (const float*)d_in[6];
    const float* W_val  = (const float*)d_in[7];
    const float* b_val  = (const float*)d_in[8];
    const float* W_out  = (const float*)d_in[9];
    const float* b_out  = (const float*)d_in[10];
    float* out = (float*)d_out;

    char* p = (char*)d_ws;
    ushort* v_bf    = (ushort*)p; p += (size_t)LQ * CDIM * 2;   // bf16 value' [8][LQ][32]
    float*  off_hm  = (float*)p;  p += (size_t)LQ * 256 * 4;    // final coords [8][LQ][32]
    float*  wts_hm  = (float*)p;  p += (size_t)LQ * 128 * 4;    // weights [8][LQ][16]
    ushort* outp    = (ushort*)p; p += (size_t)LQ * CDIM * 2;   // bf16 sampled
    ushort* Wt_val  = (ushort*)p; p += 65536 * 2;
    ushort* Wt_oa   = (ushort*)p; p += (65536 + 32768) * 2;
    ushort* Wt_out  = (ushort*)p; p += 65536 * 2;
    float*  bcat    = (float*)p;  p += 384 * 4;

    // 1. weights fp32 -> bf16 [N][K] (+ concatenated off/attn bias)
    convert_wt<<<(229376 + 384 + 255) / 256, 256, 0, stream>>>(
        W_val, W_off, W_out, W_attn, b_off, b_attn, Wt_val, Wt_oa, Wt_out, bcat);

    // 2. fused: v_bf = bf16(value@Wv + bv) [head-major]  AND
    //    final sample coords (ref folded in) + softmaxed weights, head-major
    gemm_dual<<<NBV + NBOA, 256, 0, stream>>>(
        value, Wt_val, b_val, v_bf, query, Wt_oa, bcat, ref, off_hm, wts_hm);

    // 3. deformable sampling -> outp (bf16)
    const int qg = (LQ + 63) / 64;    // 348
    msda_sample<<<qg * 8, 256, 0, stream>>>(v_bf, off_hm, wts_hm, outp);

    // 4. out = outp @ W_out + b_out
    gemm_out<<<176 * 8, 256, 0, stream>>>(outp, Wt_out, b_out, out);
}